// Round 1
// baseline (62.666 us; speedup 1.0000x reference)
//
#include <hip/hip_runtime.h>

// Kernel A: ternary-quantize the 8192-element kernel vector.
// threshold = 0.7 * sum(|w|) / n ; q = sign(w) if |w| >= t else 0.
// Single block (256 threads), block reduction in LDS.
__global__ void ternary_quant_kernel(const float* __restrict__ w,
                                     float* __restrict__ q, int n) {
    __shared__ float red[256];
    const int tid = threadIdx.x;
    float s = 0.f;
    for (int i = tid; i < n; i += 256) s += fabsf(w[i]);
    red[tid] = s;
    __syncthreads();
    for (int off = 128; off > 0; off >>= 1) {
        if (tid < off) red[tid] += red[tid + off];
        __syncthreads();
    }
    const float t = 0.7f * red[0] / (float)n;
    for (int i = tid; i < n; i += 256) {
        const float wv = w[i];
        // reference: sign(sign(w+t)+sign(w-t)) -> |w| >= t gives sign(w), else 0
        q[i] = (fabsf(wv) >= t) ? copysignf(1.f, wv) : 0.f;
    }
}

// Kernel B: out = x * q[col] + bias[col], float4-vectorized grid-stride.
// N = 8192 -> N/4 = 2048 (power of two) -> col4 = i & 2047.
__global__ __launch_bounds__(256) void scale_bias_kernel(
    const float4* __restrict__ x, const float* __restrict__ q,
    const float* __restrict__ bias, float4* __restrict__ out,
    long total4, int n4mask) {
    const long stride = (long)gridDim.x * blockDim.x;
    for (long i = (long)blockIdx.x * blockDim.x + threadIdx.x; i < total4; i += stride) {
        const int c = (int)(i & n4mask);
        const float4 xv = x[i];
        const float4 qv = reinterpret_cast<const float4*>(q)[c];
        const float4 bv = reinterpret_cast<const float4*>(bias)[c];
        float4 o;
        o.x = xv.x * qv.x + bv.x;
        o.y = xv.y * qv.y + bv.y;
        o.z = xv.z * qv.z + bv.z;
        o.w = xv.w * qv.w + bv.w;
        out[i] = o;
    }
}

extern "C" void kernel_launch(void* const* d_in, const int* in_sizes, int n_in,
                              void* d_out, int out_size, void* d_ws, size_t ws_size,
                              hipStream_t stream) {
    const float* x      = (const float*)d_in[0];
    const float* kernel = (const float*)d_in[1];
    const float* bias   = (const float*)d_in[2];
    float* out = (float*)d_out;
    float* q   = (float*)d_ws;  // N floats = 32 KiB scratch

    const int N = in_sizes[1];          // 8192
    const long total = (long)out_size;  // 4096 * 8192
    const long total4 = total / 4;
    const int n4mask = (N / 4) - 1;     // 2047

    ternary_quant_kernel<<<1, 256, 0, stream>>>(kernel, q, N);

    const int block = 256;
    long blocks = (total4 + block - 1) / block;
    if (blocks > 2048) blocks = 2048;
    scale_bias_kernel<<<(int)blocks, block, 0, stream>>>(
        (const float4*)x, q, bias, (float4*)out, total4, n4mask);
}

// Round 2
// 54.580 us; speedup vs baseline: 1.1482x; 1.1482x over previous
//
#include <hip/hip_runtime.h>

typedef float f32x4 __attribute__((ext_vector_type(4)));

// Fused: per-block redundant threshold reduction (kernel vec is 32 KB,
// L2-resident), inline ternary quantize of this thread's fixed column,
// then a pure streaming row loop.
//
// Requires (gridDim.x * 256) % (N/4) == 0 so each thread's float4-column
// index is constant across grid-stride iterations (2048*256=524288 is a
// multiple of N/4=2048).
__global__ __launch_bounds__(256) void fused_ternary_scale_bias(
    const f32x4* __restrict__ x, const float* __restrict__ w,
    const f32x4* __restrict__ bias4, f32x4* __restrict__ out,
    int n, long total4) {
    __shared__ float red[256];
    const int tid = threadIdx.x;

    // threshold = 0.7 * sum(|w|) / n, computed redundantly per block
    float s = 0.f;
    for (int i = tid; i < n; i += 256) s += fabsf(w[i]);
    red[tid] = s;
    __syncthreads();
    for (int off = 128; off > 0; off >>= 1) {
        if (tid < off) red[tid] += red[tid + off];
        __syncthreads();
    }
    const float t = 0.7f * red[0] / (float)n;

    const int n4 = n >> 2;
    const long i0 = (long)blockIdx.x * blockDim.x + tid;
    const long stride = (long)gridDim.x * blockDim.x;
    const int c = (int)(i0 & (long)(n4 - 1));  // constant for this thread

    // inline ternary quantize: |w| >= t -> sign(w), else 0
    const f32x4 wv = reinterpret_cast<const f32x4*>(w)[c];
    f32x4 qv;
    qv.x = (fabsf(wv.x) >= t) ? copysignf(1.f, wv.x) : 0.f;
    qv.y = (fabsf(wv.y) >= t) ? copysignf(1.f, wv.y) : 0.f;
    qv.z = (fabsf(wv.z) >= t) ? copysignf(1.f, wv.z) : 0.f;
    qv.w = (fabsf(wv.w) >= t) ? copysignf(1.f, wv.w) : 0.f;
    const f32x4 bv = bias4[c];

    for (long i = i0; i < total4; i += stride) {
        f32x4 xv = __builtin_nontemporal_load(&x[i]);
        f32x4 o = xv * qv + bv;
        __builtin_nontemporal_store(o, &out[i]);
    }
}

extern "C" void kernel_launch(void* const* d_in, const int* in_sizes, int n_in,
                              void* d_out, int out_size, void* d_ws, size_t ws_size,
                              hipStream_t stream) {
    const float* x      = (const float*)d_in[0];
    const float* kernel = (const float*)d_in[1];
    const float* bias   = (const float*)d_in[2];
    float* out = (float*)d_out;

    const int N = in_sizes[1];          // 8192
    const long total4 = (long)out_size / 4;

    // 2048 blocks x 256 threads: 8 blocks/CU, 16 row-iterations/thread,
    // and stride (524288) is a multiple of N/4 (2048) -> fixed column/thread.
    fused_ternary_scale_bias<<<2048, 256, 0, stream>>>(
        (const f32x4*)x, kernel, (const f32x4*)bias, (f32x4*)out, N, total4);
}